// Round 1
// baseline (258.759 us; speedup 1.0000x reference)
//
#include <hip/hip_runtime.h>
#include <hip/hip_bf16.h>
#include <stdint.h>

typedef __bf16 bf16x8_t __attribute__((ext_vector_type(8)));
typedef float f32x4_t __attribute__((ext_vector_type(4)));

#define B_SZ 2
#define T_SZ 2048
#define D_SZ 1024
#define H_SZ 16
#define M_SZ 4096                    // B*T
#define QK_SCALE 0.02209708691207961f  // 1/sqrt(2048)

__device__ __forceinline__ void gld_lds16(const void* g, void* l) {
  __builtin_amdgcn_global_load_lds(
      (const __attribute__((address_space(1))) unsigned int*)g,
      (__attribute__((address_space(3))) unsigned int*)l, 16, 0, 0);
}

// ---------------------------------------------------------------- cast kernel
__global__ __launch_bounds__(256) void cast_all_k(
    const float* __restrict__ x, const float* __restrict__ wq,
    const float* __restrict__ wk, const float* __restrict__ wv,
    const float* __restrict__ wo, __hip_bfloat16* __restrict__ dst) {
  size_t i = ((size_t)blockIdx.x * 256 + threadIdx.x) * 4;
  if (i >= 8388608) return;
  const float* src;
  size_t off;
  if (i < 4194304) { src = x; off = i; }
  else {
    size_t r = i - 4194304;
    int s = (int)(r >> 20);
    off = r & 1048575;
    src = s == 0 ? wq : s == 1 ? wk : s == 2 ? wv : wo;
  }
  float4 v = *(const float4*)(src + off);
  __hip_bfloat16 h0 = __float2bfloat16(v.x), h1 = __float2bfloat16(v.y);
  __hip_bfloat16 h2 = __float2bfloat16(v.z), h3 = __float2bfloat16(v.w);
  ushort4 u;
  u.x = *(unsigned short*)&h0; u.y = *(unsigned short*)&h1;
  u.z = *(unsigned short*)&h2; u.w = *(unsigned short*)&h3;
  *(ushort4*)(dst + i) = u;
}

// ------------------------------------------------------- shared GEMM mainloop
// C[128x128] = A[128xK] * W[128xK]^T   (both row-major, K=1024, BK=32)
// LDS tiles staged with global_load_lds (linear dest); k-chunk XOR-swizzled via
// pre-swizzled global source (chunk ^= row&3), reads undo the swizzle.
__device__ __forceinline__ void gemm_mainloop(
    const __hip_bfloat16* __restrict__ A, const __hip_bfloat16* __restrict__ W,
    int m0, int n0, __hip_bfloat16* a_lds, __hip_bfloat16* b_lds,
    f32x4_t (&acc)[4][4]) {
  const int tid = threadIdx.x;
  const int w = tid >> 6, l = tid & 63, lr = l & 15, lg = l >> 4;
  const int wm = w >> 1, wn = w & 1;
  const int c0 = tid, c1 = tid + 256;
  const int r0 = c0 >> 2, k0c = c0 & 3;
  const int r1 = c1 >> 2, k1c = c1 & 3;
  const __hip_bfloat16* ga0 = A + (size_t)(m0 + r0) * 1024 + 8 * (k0c ^ (r0 & 3));
  const __hip_bfloat16* ga1 = A + (size_t)(m0 + r1) * 1024 + 8 * (k1c ^ (r1 & 3));
  const __hip_bfloat16* gb0 = W + (size_t)(n0 + r0) * 1024 + 8 * (k0c ^ (r0 & 3));
  const __hip_bfloat16* gb1 = W + (size_t)(n0 + r1) * 1024 + 8 * (k1c ^ (r1 & 3));
  __hip_bfloat16* la0 = a_lds + w * 512;
  __hip_bfloat16* la1 = a_lds + 2048 + w * 512;
  __hip_bfloat16* lb0 = b_lds + w * 512;
  __hip_bfloat16* lb1 = b_lds + 2048 + w * 512;

  int aoff[4], boff[4];
#pragma unroll
  for (int f = 0; f < 4; ++f) {
    int ra = wm * 64 + f * 16 + lr;
    aoff[f] = ra * 32 + 8 * (lg ^ (ra & 3));
    int rb = wn * 64 + f * 16 + lr;
    boff[f] = rb * 32 + 8 * (lg ^ (rb & 3));
  }

  for (int kk = 0; kk < 1024; kk += 32) {
    gld_lds16(ga0 + kk, la0);
    gld_lds16(ga1 + kk, la1);
    gld_lds16(gb0 + kk, lb0);
    gld_lds16(gb1 + kk, lb1);
    __syncthreads();   // drains vmcnt(0): staged data visible
    bf16x8_t af[4], bfr[4];
#pragma unroll
    for (int f = 0; f < 4; ++f) {
      af[f]  = *(const bf16x8_t*)(a_lds + aoff[f]);
      bfr[f] = *(const bf16x8_t*)(b_lds + boff[f]);
    }
#pragma unroll
    for (int i = 0; i < 4; ++i)
#pragma unroll
      for (int j = 0; j < 4; ++j)
        acc[i][j] = __builtin_amdgcn_mfma_f32_16x16x32_bf16(af[i], bfr[j], acc[i][j], 0, 0, 0);
    __syncthreads();   // before next stage overwrites LDS
  }
}

// --------------------------------------------------------------- QKV GEMM
// N-space: [0,1024)=Q, [1024,2048)=K, [2048,3072)=V. Q gets (x+bq)*scale.
// V is written TRANSPOSED per head: vt[((b*16+h)*64+d)*2048 + t].
__global__ __launch_bounds__(256, 2) void gemm_qkv(
    const __hip_bfloat16* __restrict__ xb,
    const __hip_bfloat16* __restrict__ wqb, const __hip_bfloat16* __restrict__ wkb,
    const __hip_bfloat16* __restrict__ wvb,
    const float* __restrict__ bq, const float* __restrict__ bk,
    const float* __restrict__ bv,
    __hip_bfloat16* __restrict__ qo, __hip_bfloat16* __restrict__ ko,
    __hip_bfloat16* __restrict__ vto) {
  __shared__ __hip_bfloat16 a_lds[4096];
  __shared__ __hip_bfloat16 b_lds[4096];
  const int n0g = blockIdx.x * 128;     // 0..3071
  const int m0  = blockIdx.y * 128;     // 0..4095
  const int seg = n0g >> 10;            // 0=q 1=k 2=v (tile never crosses)
  const int n0  = n0g & 1023;
  const __hip_bfloat16* W = seg == 0 ? wqb : seg == 1 ? wkb : wvb;
  const float* bias = seg == 0 ? bq : seg == 1 ? bk : bv;

  f32x4_t acc[4][4] = {};
  gemm_mainloop(xb, W, m0, n0, a_lds, b_lds, acc);

  const int tid = threadIdx.x;
  const int w = tid >> 6, l = tid & 63, lr = l & 15, lg = l >> 4;
  const int wm = w >> 1, wn = w & 1;
#pragma unroll
  for (int i = 0; i < 4; ++i) {
#pragma unroll
    for (int j = 0; j < 4; ++j) {
      const int col = n0 + wn * 64 + j * 16 + lr;   // feature within segment
      const float bb = bias[col];
      f32x4_t v = acc[i][j];
#pragma unroll
      for (int e = 0; e < 4; ++e) {
        const int row = m0 + wm * 64 + i * 16 + lg * 4 + e;  // global token row
        float val = v[e] + bb;
        if (seg == 0) {
          qo[(size_t)row * 1024 + col] = __float2bfloat16(val * QK_SCALE);
        } else if (seg == 1) {
          ko[(size_t)row * 1024 + col] = __float2bfloat16(val);
        } else {
          const int h = col >> 6, d = col & 63;
          const int b = row >> 11, t = row & 2047;
          vto[((size_t)((b * 16 + h) * 64 + d)) * 2048 + t] = __float2bfloat16(val);
        }
      }
    }
  }
}

// ------------------------------------------------------------ flash attention
// grid = (T/128, B*H). 512 thr = 8 waves x 16 q-rows. KV tile = 64 keys.
// K tile [64 tok][64 d] and V^T tile [64 d][64 tok] in LDS, XOR-swizzled
// (chunk ^= row&7) via pre-swizzled global source. P goes through wave-private
// swizzled LDS (no block barrier, just lgkmcnt).
__global__ __launch_bounds__(512, 2) void attn_k(
    const __hip_bfloat16* __restrict__ q, const __hip_bfloat16* __restrict__ k,
    const __hip_bfloat16* __restrict__ vt, __hip_bfloat16* __restrict__ ctx) {
  __shared__ __hip_bfloat16 k_lds[4096];
  __shared__ __hip_bfloat16 v_lds[4096];
  __shared__ __hip_bfloat16 p_lds[8192];
  const int tid = threadIdx.x, w = tid >> 6, l = tid & 63;
  const int lr = l & 15, lg = l >> 4;
  const int bh = blockIdx.y, b = bh >> 4, h = bh & 15;
  const int q0 = blockIdx.x * 128;

  // Q fragments (held in registers, scale already folded in)
  const size_t qbase = ((size_t)(b * T_SZ + q0 + w * 16 + lr)) * 1024 + h * 64 + 8 * lg;
  const bf16x8_t aQ0 = *(const bf16x8_t*)(q + qbase);
  const bf16x8_t aQ1 = *(const bf16x8_t*)(q + qbase + 32);

  // staging: thread owns chunk tid: row=tid>>3, cc=tid&7; source pre-swizzled
  const int srow = tid >> 3, scc = tid & 7;
  const __hip_bfloat16* ksrc = k + ((size_t)(b * T_SZ + srow)) * 1024 + h * 64 + 8 * (scc ^ (srow & 7));
  const __hip_bfloat16* vsrc = vt + ((size_t)(bh * 64 + srow)) * 2048 + 8 * (scc ^ (srow & 7));
  __hip_bfloat16* kdst = k_lds + w * 512;   // wave-uniform dest
  __hip_bfloat16* vdst = v_lds + w * 512;
  __hip_bfloat16* pw = p_lds + w * 1024;    // wave-private P [16][64] swizzled

  float mj[4] = {-1e30f, -1e30f, -1e30f, -1e30f};
  float lj[4] = {0.f, 0.f, 0.f, 0.f};
  f32x4_t acc[4] = {};

  for (int kt = 0; kt < T_SZ; kt += 64) {
    gld_lds16(ksrc + (size_t)kt * 1024, kdst);
    gld_lds16(vsrc + kt, vdst);
    __syncthreads();

    // S = Q K^T  (16q x 64k per wave)
    f32x4_t sf[4];
#pragma unroll
    for (int nt = 0; nt < 4; ++nt) {
      const int row = nt * 16 + lr;
      bf16x8_t b0 = *(const bf16x8_t*)(k_lds + row * 64 + 8 * (lg ^ (row & 7)));
      bf16x8_t b1 = *(const bf16x8_t*)(k_lds + row * 64 + 8 * ((lg + 4) ^ (row & 7)));
      f32x4_t s = {};
      s = __builtin_amdgcn_mfma_f32_16x16x32_bf16(aQ0, b0, s, 0, 0, 0);
      s = __builtin_amdgcn_mfma_f32_16x16x32_bf16(aQ1, b1, s, 0, 0, 0);
      sf[nt] = s;
    }

    // online softmax (rows = lg*4+e, cols across 16 lanes x 4 frags)
#pragma unroll
    for (int e = 0; e < 4; ++e) {
      float rmax = fmaxf(fmaxf(sf[0][e], sf[1][e]), fmaxf(sf[2][e], sf[3][e]));
      rmax = fmaxf(rmax, __shfl_xor(rmax, 1, 16));
      rmax = fmaxf(rmax, __shfl_xor(rmax, 2, 16));
      rmax = fmaxf(rmax, __shfl_xor(rmax, 4, 16));
      rmax = fmaxf(rmax, __shfl_xor(rmax, 8, 16));
      const float newm = fmaxf(mj[e], rmax);
      const float sc = __expf(mj[e] - newm);
      float rsum = 0.f;
#pragma unroll
      for (int nt = 0; nt < 4; ++nt) {
        float p = __expf(sf[nt][e] - newm);
        sf[nt][e] = p;
        rsum += p;
      }
      rsum += __shfl_xor(rsum, 1, 16);
      rsum += __shfl_xor(rsum, 2, 16);
      rsum += __shfl_xor(rsum, 4, 16);
      rsum += __shfl_xor(rsum, 8, 16);
      lj[e] = lj[e] * sc + rsum;
      mj[e] = newm;
#pragma unroll
      for (int dt = 0; dt < 4; ++dt) acc[dt][e] *= sc;
    }

    // P -> wave-private LDS (bf16, swizzled)
#pragma unroll
    for (int nt = 0; nt < 4; ++nt) {
#pragma unroll
      for (int e = 0; e < 4; ++e) {
        const int row = lg * 4 + e;
        const int col = nt * 16 + lr;
        pw[row * 64 + 8 * ((col >> 3) ^ (row & 7)) + (col & 7)] =
            __float2bfloat16(sf[nt][e]);
      }
    }
    asm volatile("s_waitcnt lgkmcnt(0)" ::: "memory");

    const bf16x8_t aP0 = *(const bf16x8_t*)(pw + lr * 64 + 8 * (lg ^ (lr & 7)));
    const bf16x8_t aP1 = *(const bf16x8_t*)(pw + lr * 64 + 8 * ((lg + 4) ^ (lr & 7)));

    // ctx += P V  (B-frag contiguous thanks to V^T layout)
#pragma unroll
    for (int dt = 0; dt < 4; ++dt) {
      const int drow = dt * 16 + lr;
      bf16x8_t bv0 = *(const bf16x8_t*)(v_lds + drow * 64 + 8 * (lg ^ (drow & 7)));
      bf16x8_t bv1 = *(const bf16x8_t*)(v_lds + drow * 64 + 8 * ((lg + 4) ^ (drow & 7)));
      acc[dt] = __builtin_amdgcn_mfma_f32_16x16x32_bf16(aP0, bv0, acc[dt], 0, 0, 0);
      acc[dt] = __builtin_amdgcn_mfma_f32_16x16x32_bf16(aP1, bv1, acc[dt], 0, 0, 0);
    }
    __syncthreads();
  }

  // normalize + store ctx (bf16, [B,T,D] layout)
#pragma unroll
  for (int e = 0; e < 4; ++e) {
    const float inv = 1.0f / lj[e];
    const int row = q0 + w * 16 + lg * 4 + e;
#pragma unroll
    for (int dt = 0; dt < 4; ++dt) {
      const int d = dt * 16 + lr;
      ctx[((size_t)(b * T_SZ + row)) * 1024 + h * 64 + d] =
          __float2bfloat16(acc[dt][e] * inv);
    }
  }
}

// ----------------------------------------------------------------- out GEMM
__global__ __launch_bounds__(256, 2) void gemm_out(
    const __hip_bfloat16* __restrict__ ctx, const __hip_bfloat16* __restrict__ wob,
    const float* __restrict__ bo, float* __restrict__ out) {
  __shared__ __hip_bfloat16 a_lds[4096];
  __shared__ __hip_bfloat16 b_lds[4096];
  const int n0 = blockIdx.x * 128, m0 = blockIdx.y * 128;
  f32x4_t acc[4][4] = {};
  gemm_mainloop(ctx, wob, m0, n0, a_lds, b_lds, acc);
  const int tid = threadIdx.x;
  const int w = tid >> 6, l = tid & 63, lr = l & 15, lg = l >> 4;
  const int wm = w >> 1, wn = w & 1;
#pragma unroll
  for (int i = 0; i < 4; ++i) {
#pragma unroll
    for (int j = 0; j < 4; ++j) {
      const int col = n0 + wn * 64 + j * 16 + lr;
      const float bb = bo[col];
      f32x4_t v = acc[i][j];
#pragma unroll
      for (int e = 0; e < 4; ++e) {
        const int row = m0 + wm * 64 + i * 16 + lg * 4 + e;
        out[(size_t)row * 1024 + col] = v[e] + bb;
      }
    }
  }
}

// ------------------------------------------------------------------- launch
extern "C" void kernel_launch(void* const* d_in, const int* in_sizes, int n_in,
                              void* d_out, int out_size, void* d_ws, size_t ws_size,
                              hipStream_t stream) {
  const float* x  = (const float*)d_in[0];
  const float* wq = (const float*)d_in[1];
  const float* bq = (const float*)d_in[2];
  const float* wk = (const float*)d_in[3];
  const float* bk = (const float*)d_in[4];
  const float* wv = (const float*)d_in[5];
  const float* bv = (const float*)d_in[6];
  const float* wo = (const float*)d_in[7];
  const float* bo = (const float*)d_in[8];
  float* out = (float*)d_out;

  __hip_bfloat16* ws = (__hip_bfloat16*)d_ws;
  __hip_bfloat16* xb  = ws;                 // 4M elems
  __hip_bfloat16* wqb = xb + 4194304;       // 1M
  __hip_bfloat16* wkb = wqb + 1048576;
  __hip_bfloat16* wvb = wkb + 1048576;
  __hip_bfloat16* wob = wvb + 1048576;
  __hip_bfloat16* qb  = wob + 1048576;      // 4M
  __hip_bfloat16* kb  = qb + 4194304;       // 4M
  __hip_bfloat16* vtb = kb + 4194304;       // 4M (transposed per head)
  __hip_bfloat16* ctxb = vtb + 4194304;     // 4M   -> total 24M elems = 48MB

  cast_all_k<<<8192, 256, 0, stream>>>(x, wq, wk, wv, wo, xb);
  gemm_qkv<<<dim3(24, 32), 256, 0, stream>>>(xb, wqb, wkb, wvb, bq, bk, bv, qb, kb, vtb);
  attn_k<<<dim3(16, 32), 512, 0, stream>>>(qb, kb, vtb, ctxb);
  gemm_out<<<dim3(8, 32), 256, 0, stream>>>(ctxb, wob, bo, out);
}

// Round 8
// 208.303 us; speedup vs baseline: 1.2422x; 1.2422x over previous
//
#include <hip/hip_runtime.h>
#include <hip/hip_bf16.h>
#include <stdint.h>

typedef __bf16 bf16x8_t __attribute__((ext_vector_type(8)));
typedef float f32x4_t __attribute__((ext_vector_type(4)));

#define B_SZ 2
#define T_SZ 2048
#define D_SZ 1024
#define H_SZ 16
#define M_SZ 4096                    // B*T
// 1/sqrt(2048) * log2(e): scores land in log2 domain -> raw v_exp_f32
#define QK_SCALE (0.02209708691207961f * 1.4426950408889634f)

__device__ __forceinline__ void gld_lds16(const void* g, void* l) {
  __builtin_amdgcn_global_load_lds(
      (const __attribute__((address_space(1))) unsigned int*)g,
      (__attribute__((address_space(3))) unsigned int*)l, 16, 0, 0);
}

// XCD-aware chunked swizzle of a linear block id. REQUIRES nwg % 8 == 0
// (both GEMM grids: 768 and 256). Bijective: (bid%8)*(nwg/8) + bid/8.
__device__ __forceinline__ int xcd_swz(int bid, int nwg) {
  return (bid & 7) * (nwg >> 3) + (bid >> 3);
}

// ---------------------------------------------------------------- cast kernel
__global__ __launch_bounds__(256) void cast_all_k(
    const float* __restrict__ x, const float* __restrict__ wq,
    const float* __restrict__ wk, const float* __restrict__ wv,
    const float* __restrict__ wo, __hip_bfloat16* __restrict__ dst) {
  size_t i = ((size_t)blockIdx.x * 256 + threadIdx.x) * 4;
  if (i >= 8388608) return;
  const float* src;
  size_t off;
  if (i < 4194304) { src = x; off = i; }
  else {
    size_t r = i - 4194304;
    int s = (int)(r >> 20);
    off = r & 1048575;
    src = s == 0 ? wq : s == 1 ? wk : s == 2 ? wv : wo;
  }
  float4 v = *(const float4*)(src + off);
  __hip_bfloat16 h0 = __float2bfloat16(v.x), h1 = __float2bfloat16(v.y);
  __hip_bfloat16 h2 = __float2bfloat16(v.z), h3 = __float2bfloat16(v.w);
  ushort4 u;
  u.x = *(unsigned short*)&h0; u.y = *(unsigned short*)&h1;
  u.z = *(unsigned short*)&h2; u.w = *(unsigned short*)&h3;
  *(ushort4*)(dst + i) = u;
}

// ------------------------------------------------------- shared GEMM mainloop
// C[128x128] = A[128xK] * W[128xK]^T   (both row-major, K=1024, BK=32)
__device__ __forceinline__ void gemm_mainloop(
    const __hip_bfloat16* __restrict__ A, const __hip_bfloat16* __restrict__ W,
    int m0, int n0, __hip_bfloat16* a_lds, __hip_bfloat16* b_lds,
    f32x4_t (&acc)[4][4]) {
  const int tid = threadIdx.x;
  const int w = tid >> 6, l = tid & 63, lr = l & 15, lg = l >> 4;
  const int wm = w >> 1, wn = w & 1;
  const int c0 = tid, c1 = tid + 256;
  const int r0 = c0 >> 2, k0c = c0 & 3;
  const int r1 = c1 >> 2, k1c = c1 & 3;
  const __hip_bfloat16* ga0 = A + (size_t)(m0 + r0) * 1024 + 8 * (k0c ^ (r0 & 3));
  const __hip_bfloat16* ga1 = A + (size_t)(m0 + r1) * 1024 + 8 * (k1c ^ (r1 & 3));
  const __hip_bfloat16* gb0 = W + (size_t)(n0 + r0) * 1024 + 8 * (k0c ^ (r0 & 3));
  const __hip_bfloat16* gb1 = W + (size_t)(n0 + r1) * 1024 + 8 * (k1c ^ (r1 & 3));
  __hip_bfloat16* la0 = a_lds + w * 512;
  __hip_bfloat16* la1 = a_lds + 2048 + w * 512;
  __hip_bfloat16* lb0 = b_lds + w * 512;
  __hip_bfloat16* lb1 = b_lds + 2048 + w * 512;

  int aoff[4], boff[4];
#pragma unroll
  for (int f = 0; f < 4; ++f) {
    int ra = wm * 64 + f * 16 + lr;
    aoff[f] = ra * 32 + 8 * (lg ^ (ra & 3));
    int rb = wn * 64 + f * 16 + lr;
    boff[f] = rb * 32 + 8 * (lg ^ (rb & 3));
  }

  for (int kk = 0; kk < 1024; kk += 32) {
    gld_lds16(ga0 + kk, la0);
    gld_lds16(ga1 + kk, la1);
    gld_lds16(gb0 + kk, lb0);
    gld_lds16(gb1 + kk, lb1);
    __syncthreads();
    bf16x8_t af[4], bfr[4];
#pragma unroll
    for (int f = 0; f < 4; ++f) {
      af[f]  = *(const bf16x8_t*)(a_lds + aoff[f]);
      bfr[f] = *(const bf16x8_t*)(b_lds + boff[f]);
    }
#pragma unroll
    for (int i = 0; i < 4; ++i)
#pragma unroll
      for (int j = 0; j < 4; ++j)
        acc[i][j] = __builtin_amdgcn_mfma_f32_16x16x32_bf16(af[i], bfr[j], acc[i][j], 0, 0, 0);
    __syncthreads();
  }
}

// --------------------------------------------------------------- QKV GEMM
__global__ __launch_bounds__(256, 2) void gemm_qkv(
    const __hip_bfloat16* __restrict__ xb,
    const __hip_bfloat16* __restrict__ wqb, const __hip_bfloat16* __restrict__ wkb,
    const __hip_bfloat16* __restrict__ wvb,
    const float* __restrict__ bq, const float* __restrict__ bk,
    const float* __restrict__ bv,
    __hip_bfloat16* __restrict__ qo, __hip_bfloat16* __restrict__ ko,
    __hip_bfloat16* __restrict__ vto) {
  __shared__ __hip_bfloat16 a_lds[4096];
  __shared__ __hip_bfloat16 b_lds[4096];
  // XCD swizzle: grid (24,32) -> 768 tiles; each XCD gets 96 consecutive
  // tiles (= 4 full A-row-panels) for L2 residency of the A panel.
  const int lin = xcd_swz(blockIdx.y * 24 + blockIdx.x, 768);
  const int bx = lin % 24, by = lin / 24;
  const int n0g = bx * 128;
  const int m0  = by * 128;
  const int seg = n0g >> 10;            // 0=q 1=k 2=v
  const int n0  = n0g & 1023;
  const __hip_bfloat16* W = seg == 0 ? wqb : seg == 1 ? wkb : wvb;
  const float* bias = seg == 0 ? bq : seg == 1 ? bk : bv;

  f32x4_t acc[4][4] = {};
  gemm_mainloop(xb, W, m0, n0, a_lds, b_lds, acc);

  const int tid = threadIdx.x;
  const int w = tid >> 6, l = tid & 63, lr = l & 15, lg = l >> 4;
  const int wm = w >> 1, wn = w & 1;
#pragma unroll
  for (int i = 0; i < 4; ++i) {
#pragma unroll
    for (int j = 0; j < 4; ++j) {
      const int col = n0 + wn * 64 + j * 16 + lr;
      const float bb = bias[col];
      f32x4_t v = acc[i][j];
      const int row0 = m0 + wm * 64 + i * 16 + lg * 4;
      if (seg == 0) {
#pragma unroll
        for (int e = 0; e < 4; ++e)
          qo[(size_t)(row0 + e) * 1024 + col] = __float2bfloat16((v[e] + bb) * QK_SCALE);
      } else if (seg == 1) {
#pragma unroll
        for (int e = 0; e < 4; ++e)
          ko[(size_t)(row0 + e) * 1024 + col] = __float2bfloat16(v[e] + bb);
      } else {
        // V transposed per head: vt[((b*16+h)*64+d)*2048 + t]; e -> consecutive t
        const int h = col >> 6, d = col & 63;
        const int b = row0 >> 11, t0 = row0 & 2047;
        union { unsigned short s[4]; uint2 u; } pk;
#pragma unroll
        for (int e = 0; e < 4; ++e) {
          __hip_bfloat16 hv = __float2bfloat16(v[e] + bb);
          pk.s[e] = *(unsigned short*)&hv;
        }
        *(uint2*)(vto + ((size_t)((b * 16 + h) * 64 + d)) * 2048 + t0) = pk.u;
      }
    }
  }
}

// ------------------------------------------------------------ flash attention
// grid = (T/128, B*H). 512 thr = 8 waves x 16 q-rows. KV tile = 64 keys,
// double-buffered, counted vmcnt(2), raw s_barrier (loads span barriers).
// Swapped QK^T: lane owns one q-row (q=lr) x 16 scores in-lane -> in-lane
// softmax reduce + 2 shfl_xor; P write is 4x ds_write_b64 (packed, swizzled).
__global__ __launch_bounds__(512, 4) void attn_k(
    const __hip_bfloat16* __restrict__ q, const __hip_bfloat16* __restrict__ k,
    const __hip_bfloat16* __restrict__ vt, __hip_bfloat16* __restrict__ ctx) {
  __shared__ __hip_bfloat16 k_lds[2][4096];
  __shared__ __hip_bfloat16 v_lds[2][4096];
  __shared__ __hip_bfloat16 p_lds[8192];
  const int tid = threadIdx.x, w = tid >> 6, l = tid & 63;
  const int lr = l & 15, lg = l >> 4;
  const int bh = blockIdx.y, b = bh >> 4, h = bh & 15;
  const int q0 = blockIdx.x * 128;

  // staging addresses (source pre-swizzled, LDS dest linear)
  const int srow = tid >> 3, scc = tid & 7;
  const __hip_bfloat16* ksrc = k + ((size_t)(b * T_SZ + srow)) * 1024 + h * 64 + 8 * (scc ^ (srow & 7));
  const __hip_bfloat16* vsrc = vt + ((size_t)(bh * 64 + srow)) * 2048 + 8 * (scc ^ (srow & 7));
  __hip_bfloat16* kdst0 = &k_lds[0][0] + w * 512;
  __hip_bfloat16* kdst1 = &k_lds[1][0] + w * 512;
  __hip_bfloat16* vdst0 = &v_lds[0][0] + w * 512;
  __hip_bfloat16* vdst1 = &v_lds[1][0] + w * 512;
  __hip_bfloat16* pw = p_lds + w * 1024;   // wave-private P [16 q][64 k] swizzled

  // prologue: stage tile 0 into buffer 0
  gld_lds16(ksrc, kdst0);
  gld_lds16(vsrc, vdst0);

  // Q fragments (scale incl. log2e folded in)
  const size_t qbase = ((size_t)(b * T_SZ + q0 + w * 16 + lr)) * 1024 + h * 64 + 8 * lg;
  const bf16x8_t aQ0 = *(const bf16x8_t*)(q + qbase);
  const bf16x8_t aQ1 = *(const bf16x8_t*)(q + qbase + 32);

  float mrow = -1e30f, lrow = 0.f;
  f32x4_t acc[4] = {};

  auto tile = [&](const __hip_bfloat16* kr, const __hip_bfloat16* vr,
                  bool pf, int tn, __hip_bfloat16* kd, __hip_bfloat16* vd) {
    if (pf) {
      gld_lds16(ksrc + (size_t)tn * 64 * 1024, kd);
      gld_lds16(vsrc + tn * 64, vd);
      asm volatile("s_waitcnt vmcnt(2)" ::: "memory");
    } else {
      asm volatile("s_waitcnt vmcnt(0)" ::: "memory");
    }
    __builtin_amdgcn_s_barrier();
    asm volatile("" ::: "memory");

    // S^T = K Q^T : lane holds S[q=lr][k = nt*16 + lg*4 + e]
    f32x4_t sf[4];
#pragma unroll
    for (int nt = 0; nt < 4; ++nt) {
      const int row = nt * 16 + lr;
      bf16x8_t b0 = *(const bf16x8_t*)(kr + row * 64 + 8 * (lg ^ (row & 7)));
      bf16x8_t b1 = *(const bf16x8_t*)(kr + row * 64 + 8 * ((lg + 4) ^ (row & 7)));
      f32x4_t s = {};
      s = __builtin_amdgcn_mfma_f32_16x16x32_bf16(b0, aQ0, s, 0, 0, 0);
      s = __builtin_amdgcn_mfma_f32_16x16x32_bf16(b1, aQ1, s, 0, 0, 0);
      sf[nt] = s;
    }

    // online softmax, log2 domain: in-lane 16 + 2 shfl_xor across lg-groups
    float tmax = sf[0][0];
#pragma unroll
    for (int nt = 0; nt < 4; ++nt)
#pragma unroll
      for (int e = 0; e < 4; ++e) tmax = fmaxf(tmax, sf[nt][e]);
    tmax = fmaxf(tmax, __shfl_xor(tmax, 16));
    tmax = fmaxf(tmax, __shfl_xor(tmax, 32));
    const float newm = fmaxf(mrow, tmax);
    const float sc = __builtin_amdgcn_exp2f(mrow - newm);
    float rsum = 0.f;
#pragma unroll
    for (int nt = 0; nt < 4; ++nt)
#pragma unroll
      for (int e = 0; e < 4; ++e) {
        float p = __builtin_amdgcn_exp2f(sf[nt][e] - newm);
        sf[nt][e] = p;
        rsum += p;
      }
    rsum += __shfl_xor(rsum, 16);
    rsum += __shfl_xor(rsum, 32);
    lrow = lrow * sc + rsum;
    mrow = newm;

    // P -> wave-private LDS: 4 packed b64 writes (k-contiguous per lane)
#pragma unroll
    for (int nt = 0; nt < 4; ++nt) {
      union { unsigned short s[4]; uint2 u; } pk;
#pragma unroll
      for (int e = 0; e < 4; ++e) {
        __hip_bfloat16 hv = __float2bfloat16(sf[nt][e]);
        pk.s[e] = *(unsigned short*)&hv;
      }
      const int off = lr * 64 + 8 * ((nt * 2 + (lg >> 1)) ^ (lr & 7)) + (lg & 1) * 4;
      *(uint2*)(pw + off) = pk.u;
    }

    // rescale acc by per-q factor (broadcast from lane lr=q within 16-group)
    float sce[4];
#pragma unroll
    for (int e = 0; e < 4; ++e) sce[e] = __shfl(sc, lg * 4 + e, 16);
#pragma unroll
    for (int dt = 0; dt < 4; ++dt)
#pragma unroll
      for (int e = 0; e < 4; ++e) acc[dt][e] *= sce[e];

    asm volatile("s_waitcnt lgkmcnt(0)" ::: "memory");
    const bf16x8_t aP0 = *(const bf16x8_t*)(pw + lr * 64 + 8 * (lg ^ (lr & 7)));
    const bf16x8_t aP1 = *(const bf16x8_t*)(pw + lr * 64 + 8 * ((lg + 4) ^ (lr & 7)));

    // ctx += P V
#pragma unroll
    for (int dt = 0; dt < 4; ++dt) {
      const int drow = dt * 16 + lr;
      bf16x8_t bv0 = *(const bf16x8_t*)(vr + drow * 64 + 8 * (lg ^ (drow & 7)));
      bf16x8_t bv1 = *(const bf16x8_t*)(vr + drow * 64 + 8 * ((lg + 4) ^ (drow & 7)));
      acc[dt] = __builtin_amdgcn_mfma_f32_16x16x32_bf16(aP0, bv0, acc[dt], 0, 0, 0);
      acc[dt] = __builtin_amdgcn_mfma_f32_16x16x32_bf16(aP1, bv1, acc[dt], 0, 0, 0);
    }
    asm volatile("" ::: "memory");
    __builtin_amdgcn_s_barrier();
  };

  const __hip_bfloat16* kb0 = &k_lds[0][0];
  const __hip_bfloat16* kb1 = &k_lds[1][0];
  const __hip_bfloat16* vb0 = &v_lds[0][0];
  const __hip_bfloat16* vb1 = &v_lds[1][0];
#pragma unroll 1
  for (int p = 0; p < 16; ++p) {
    tile(kb0, vb0, true, 2 * p + 1, kdst1, vdst1);
    tile(kb1, vb1, p < 15, 2 * p + 2, kdst0, vdst0);
  }

  // normalize + store ctx: q = lg*4+e, broadcast 1/l from lane lr=q
  const float inv = 1.0f / lrow;
  float inve[4];
#pragma unroll
  for (int e = 0; e < 4; ++e) inve[e] = __shfl(inv, lg * 4 + e, 16);
#pragma unroll
  for (int e = 0; e < 4; ++e) {
    const int row = q0 + w * 16 + lg * 4 + e;
#pragma unroll
    for (int dt = 0; dt < 4; ++dt) {
      const int d = dt * 16 + lr;
      ctx[((size_t)(b * T_SZ + row)) * 1024 + h * 64 + d] =
          __float2bfloat16(acc[dt][e] * inve[e]);
    }
  }
}

// ----------------------------------------------------------------- out GEMM
__global__ __launch_bounds__(256, 2) void gemm_out(
    const __hip_bfloat16* __restrict__ ctx, const __hip_bfloat16* __restrict__ wob,
    const float* __restrict__ bo, float* __restrict__ out) {
  __shared__ __hip_bfloat16 a_lds[4096];
  __shared__ __hip_bfloat16 b_lds[4096];
  // XCD swizzle: grid (8,32) -> 256 tiles; 32 consecutive tiles per XCD.
  const int lin = xcd_swz(blockIdx.y * 8 + blockIdx.x, 256);
  const int n0 = (lin % 8) * 128, m0 = (lin / 8) * 128;
  f32x4_t acc[4][4] = {};
  gemm_mainloop(ctx, wob, m0, n0, a_lds, b_lds, acc);
  const int tid = threadIdx.x;
  const int w = tid >> 6, l = tid & 63, lr = l & 15, lg = l >> 4;
  const int wm = w >> 1, wn = w & 1;
#pragma unroll
  for (int i = 0; i < 4; ++i) {
#pragma unroll
    for (int j = 0; j < 4; ++j) {
      const int col = n0 + wn * 64 + j * 16 + lr;
      const float bb = bo[col];
      f32x4_t v = acc[i][j];
#pragma unroll
      for (int e = 0; e < 4; ++e) {
        const int row = m0 + wm * 64 + i * 16 + lg * 4 + e;
        out[(size_t)row * 1024 + col] = v[e] + bb;
      }
    }
  }
}

// ------------------------------------------------------------------- launch
extern "C" void kernel_launch(void* const* d_in, const int* in_sizes, int n_in,
                              void* d_out, int out_size, void* d_ws, size_t ws_size,
                              hipStream_t stream) {
  const float* x  = (const float*)d_in[0];
  const float* wq = (const float*)d_in[1];
  const float* bq = (const float*)d_in[2];
  const float* wk = (const float*)d_in[3];
  const float* bk = (const float*)d_in[4];
  const float* wv = (const float*)d_in[5];
  const float* bv = (const float*)d_in[6];
  const float* wo = (const float*)d_in[7];
  const float* bo = (const float*)d_in[8];
  float* out = (float*)d_out;

  __hip_bfloat16* ws = (__hip_bfloat16*)d_ws;
  __hip_bfloat16* xb  = ws;
  __hip_bfloat16* wqb = xb + 4194304;
  __hip_bfloat16* wkb = wqb + 1048576;
  __hip_bfloat16* wvb = wkb + 1048576;
  __hip_bfloat16* wob = wvb + 1048576;
  __hip_bfloat16* qb  = wob + 1048576;
  __hip_bfloat16* kb  = qb + 4194304;
  __hip_bfloat16* vtb = kb + 4194304;
  __hip_bfloat16* ctxb = vtb + 4194304;

  cast_all_k<<<8192, 256, 0, stream>>>(x, wq, wk, wv, wo, xb);
  gemm_qkv<<<dim3(24, 32), 256, 0, stream>>>(xb, wqb, wkb, wvb, bq, bk, bv, qb, kb, vtb);
  attn_k<<<dim3(16, 32), 512, 0, stream>>>(qb, kb, vtb, ctxb);
  gemm_out<<<dim3(8, 32), 256, 0, stream>>>(ctxb, wob, bo, out);
}

// Round 11
// 203.964 us; speedup vs baseline: 1.2687x; 1.0213x over previous
//
#include <hip/hip_runtime.h>
#include <hip/hip_bf16.h>
#include <stdint.h>

typedef __bf16 bf16x8_t __attribute__((ext_vector_type(8)));
typedef float f32x4_t __attribute__((ext_vector_type(4)));

#define B_SZ 2
#define T_SZ 2048
#define D_SZ 1024
#define H_SZ 16
#define M_SZ 4096                    // B*T
// 1/sqrt(2048) * log2(e): scores land in log2 domain -> raw v_exp_f32
#define QK_SCALE (0.02209708691207961f * 1.4426950408889634f)

__device__ __forceinline__ void gld_lds16(const void* g, void* l) {
  __builtin_amdgcn_global_load_lds(
      (const __attribute__((address_space(1))) unsigned int*)g,
      (__attribute__((address_space(3))) unsigned int*)l, 16, 0, 0);
}

// XCD-aware chunked swizzle of a linear block id. REQUIRES nwg % 8 == 0
// (both GEMM grids: 768 and 256). Bijective: (bid%8)*(nwg/8) + bid/8.
__device__ __forceinline__ int xcd_swz(int bid, int nwg) {
  return (bid & 7) * (nwg >> 3) + (bid >> 3);
}

// ---------------------------------------------------------------- cast kernel
__global__ __launch_bounds__(256) void cast_all_k(
    const float* __restrict__ x, const float* __restrict__ wq,
    const float* __restrict__ wk, const float* __restrict__ wv,
    const float* __restrict__ wo, __hip_bfloat16* __restrict__ dst) {
  size_t i = ((size_t)blockIdx.x * 256 + threadIdx.x) * 4;
  if (i >= 8388608) return;
  const float* src;
  size_t off;
  if (i < 4194304) { src = x; off = i; }
  else {
    size_t r = i - 4194304;
    int s = (int)(r >> 20);
    off = r & 1048575;
    src = s == 0 ? wq : s == 1 ? wk : s == 2 ? wv : wo;
  }
  float4 v = *(const float4*)(src + off);
  __hip_bfloat16 h0 = __float2bfloat16(v.x), h1 = __float2bfloat16(v.y);
  __hip_bfloat16 h2 = __float2bfloat16(v.z), h3 = __float2bfloat16(v.w);
  ushort4 u;
  u.x = *(unsigned short*)&h0; u.y = *(unsigned short*)&h1;
  u.z = *(unsigned short*)&h2; u.w = *(unsigned short*)&h3;
  *(ushort4*)(dst + i) = u;
}

// ------------------------------------------------------- shared GEMM mainloop
// C[128x128] = A[128xK] * W[128xK]^T  (row-major, K=1024, BK=32).
// DOUBLE-BUFFERED (validated pattern from attn_k): prologue stages buf0;
// each iter prefetches buf^1, waits counted vmcnt(4) (current tile's 4 loads
// landed, prefetch stays in flight across the barrier), raw s_barrier.
// a_lds/b_lds are [2][4096] bf16.
__device__ __forceinline__ void gemm_mainloop(
    const __hip_bfloat16* __restrict__ A, const __hip_bfloat16* __restrict__ W,
    int m0, int n0, __hip_bfloat16* a_lds, __hip_bfloat16* b_lds,
    f32x4_t (&acc)[4][4]) {
  const int tid = threadIdx.x;
  const int w = tid >> 6, l = tid & 63, lr = l & 15, lg = l >> 4;
  const int wm = w >> 1, wn = w & 1;
  const int c0 = tid, c1 = tid + 256;
  const int r0 = c0 >> 2, k0c = c0 & 3;
  const int r1 = c1 >> 2, k1c = c1 & 3;
  const __hip_bfloat16* ga0 = A + (size_t)(m0 + r0) * 1024 + 8 * (k0c ^ (r0 & 3));
  const __hip_bfloat16* ga1 = A + (size_t)(m0 + r1) * 1024 + 8 * (k1c ^ (r1 & 3));
  const __hip_bfloat16* gb0 = W + (size_t)(n0 + r0) * 1024 + 8 * (k0c ^ (r0 & 3));
  const __hip_bfloat16* gb1 = W + (size_t)(n0 + r1) * 1024 + 8 * (k1c ^ (r1 & 3));

  int aoff[4], boff[4];
#pragma unroll
  for (int f = 0; f < 4; ++f) {
    int ra = wm * 64 + f * 16 + lr;
    aoff[f] = ra * 32 + 8 * (lg ^ (ra & 3));
    int rb = wn * 64 + f * 16 + lr;
    boff[f] = rb * 32 + 8 * (lg ^ (rb & 3));
  }

  auto STAGE = [&](int kk, int buf) {
    __hip_bfloat16* la = a_lds + buf * 4096;
    __hip_bfloat16* lb = b_lds + buf * 4096;
    gld_lds16(ga0 + kk, la + w * 512);
    gld_lds16(ga1 + kk, la + 2048 + w * 512);
    gld_lds16(gb0 + kk, lb + w * 512);
    gld_lds16(gb1 + kk, lb + 2048 + w * 512);
  };
  auto COMPUTE = [&](int buf) {
    const __hip_bfloat16* la = a_lds + buf * 4096;
    const __hip_bfloat16* lb = b_lds + buf * 4096;
    bf16x8_t af[4], bfr[4];
#pragma unroll
    for (int f = 0; f < 4; ++f) {
      af[f]  = *(const bf16x8_t*)(la + aoff[f]);
      bfr[f] = *(const bf16x8_t*)(lb + boff[f]);
    }
#pragma unroll
    for (int i = 0; i < 4; ++i)
#pragma unroll
      for (int j = 0; j < 4; ++j)
        acc[i][j] = __builtin_amdgcn_mfma_f32_16x16x32_bf16(af[i], bfr[j], acc[i][j], 0, 0, 0);
  };

  STAGE(0, 0);                       // 4 outstanding
  for (int t = 0; t < 31; ++t) {
    STAGE((t + 1) * 32, (t + 1) & 1);            // 8 outstanding
    asm volatile("s_waitcnt vmcnt(4)" ::: "memory");  // current tile landed
    __builtin_amdgcn_s_barrier();
    asm volatile("" ::: "memory");
    COMPUTE(t & 1);
    asm volatile("" ::: "memory");
    __builtin_amdgcn_s_barrier();    // reads done before prefetch overwrite
  }
  asm volatile("s_waitcnt vmcnt(0)" ::: "memory");
  __builtin_amdgcn_s_barrier();
  asm volatile("" ::: "memory");
  COMPUTE(1);                        // t=31 -> buf 1
}

// --------------------------------------------------------------- QKV GEMM
__global__ __launch_bounds__(256, 2) void gemm_qkv(
    const __hip_bfloat16* __restrict__ xb,
    const __hip_bfloat16* __restrict__ wqb, const __hip_bfloat16* __restrict__ wkb,
    const __hip_bfloat16* __restrict__ wvb,
    const float* __restrict__ bq, const float* __restrict__ bk,
    const float* __restrict__ bv,
    __hip_bfloat16* __restrict__ qo, __hip_bfloat16* __restrict__ ko,
    __hip_bfloat16* __restrict__ vto) {
  __shared__ __hip_bfloat16 a_lds[8192];   // 2 buffers x 4096
  __shared__ __hip_bfloat16 b_lds[8192];
  // XCD swizzle: grid (24,32) -> 768 tiles; each XCD gets 96 consecutive
  // tiles (= 4 full A-row-panels) for L2 residency of the A panel.
  const int lin = xcd_swz(blockIdx.y * 24 + blockIdx.x, 768);
  const int bx = lin % 24, by = lin / 24;
  const int n0g = bx * 128;
  const int m0  = by * 128;
  const int seg = n0g >> 10;            // 0=q 1=k 2=v
  const int n0  = n0g & 1023;
  const __hip_bfloat16* W = seg == 0 ? wqb : seg == 1 ? wkb : wvb;
  const float* bias = seg == 0 ? bq : seg == 1 ? bk : bv;

  f32x4_t acc[4][4] = {};
  gemm_mainloop(xb, W, m0, n0, a_lds, b_lds, acc);

  const int tid = threadIdx.x;
  const int w = tid >> 6, l = tid & 63, lr = l & 15, lg = l >> 4;
  const int wm = w >> 1, wn = w & 1;
#pragma unroll
  for (int i = 0; i < 4; ++i) {
#pragma unroll
    for (int j = 0; j < 4; ++j) {
      const int col = n0 + wn * 64 + j * 16 + lr;
      const float bb = bias[col];
      f32x4_t v = acc[i][j];
      const int row0 = m0 + wm * 64 + i * 16 + lg * 4;
      if (seg == 0) {
#pragma unroll
        for (int e = 0; e < 4; ++e)
          qo[(size_t)(row0 + e) * 1024 + col] = __float2bfloat16((v[e] + bb) * QK_SCALE);
      } else if (seg == 1) {
#pragma unroll
        for (int e = 0; e < 4; ++e)
          ko[(size_t)(row0 + e) * 1024 + col] = __float2bfloat16(v[e] + bb);
      } else {
        // V transposed per head: vt[((b*16+h)*64+d)*2048 + t]; e -> consecutive t
        const int h = col >> 6, d = col & 63;
        const int b = row0 >> 11, t0 = row0 & 2047;
        union { unsigned short s[4]; uint2 u; } pk;
#pragma unroll
        for (int e = 0; e < 4; ++e) {
          __hip_bfloat16 hv = __float2bfloat16(v[e] + bb);
          pk.s[e] = *(unsigned short*)&hv;
        }
        *(uint2*)(vto + ((size_t)((b * 16 + h) * 64 + d)) * 2048 + t0) = pk.u;
      }
    }
  }
}

// ------------------------------------------------------------ flash attention
// grid = (T/128, B*H). 512 thr = 8 waves x 16 q-rows. KV tile = 64 keys,
// double-buffered, counted vmcnt(2), raw s_barrier (loads span barriers).
// Swapped QK^T: lane owns one q-row (q=lr) x 16 scores in-lane -> in-lane
// softmax reduce + 2 shfl_xor; P write is 4x ds_write_b64 (packed, swizzled).
__global__ __launch_bounds__(512, 4) void attn_k(
    const __hip_bfloat16* __restrict__ q, const __hip_bfloat16* __restrict__ k,
    const __hip_bfloat16* __restrict__ vt, __hip_bfloat16* __restrict__ ctx) {
  __shared__ __hip_bfloat16 k_lds[2][4096];
  __shared__ __hip_bfloat16 v_lds[2][4096];
  __shared__ __hip_bfloat16 p_lds[8192];
  const int tid = threadIdx.x, w = tid >> 6, l = tid & 63;
  const int lr = l & 15, lg = l >> 4;
  const int bh = blockIdx.y, b = bh >> 4, h = bh & 15;
  const int q0 = blockIdx.x * 128;

  // staging addresses (source pre-swizzled, LDS dest linear)
  const int srow = tid >> 3, scc = tid & 7;
  const __hip_bfloat16* ksrc = k + ((size_t)(b * T_SZ + srow)) * 1024 + h * 64 + 8 * (scc ^ (srow & 7));
  const __hip_bfloat16* vsrc = vt + ((size_t)(bh * 64 + srow)) * 2048 + 8 * (scc ^ (srow & 7));
  __hip_bfloat16* kdst0 = &k_lds[0][0] + w * 512;
  __hip_bfloat16* kdst1 = &k_lds[1][0] + w * 512;
  __hip_bfloat16* vdst0 = &v_lds[0][0] + w * 512;
  __hip_bfloat16* vdst1 = &v_lds[1][0] + w * 512;
  __hip_bfloat16* pw = p_lds + w * 1024;   // wave-private P [16 q][64 k] swizzled

  // prologue: stage tile 0 into buffer 0
  gld_lds16(ksrc, kdst0);
  gld_lds16(vsrc, vdst0);

  // Q fragments (scale incl. log2e folded in)
  const size_t qbase = ((size_t)(b * T_SZ + q0 + w * 16 + lr)) * 1024 + h * 64 + 8 * lg;
  const bf16x8_t aQ0 = *(const bf16x8_t*)(q + qbase);
  const bf16x8_t aQ1 = *(const bf16x8_t*)(q + qbase + 32);

  float mrow = -1e30f, lrow = 0.f;
  f32x4_t acc[4] = {};

  auto tile = [&](const __hip_bfloat16* kr, const __hip_bfloat16* vr,
                  bool pf, int tn, __hip_bfloat16* kd, __hip_bfloat16* vd) {
    if (pf) {
      gld_lds16(ksrc + (size_t)tn * 64 * 1024, kd);
      gld_lds16(vsrc + tn * 64, vd);
      asm volatile("s_waitcnt vmcnt(2)" ::: "memory");
    } else {
      asm volatile("s_waitcnt vmcnt(0)" ::: "memory");
    }
    __builtin_amdgcn_s_barrier();
    asm volatile("" ::: "memory");

    // S^T = K Q^T : lane holds S[q=lr][k = nt*16 + lg*4 + e]
    f32x4_t sf[4];
#pragma unroll
    for (int nt = 0; nt < 4; ++nt) {
      const int row = nt * 16 + lr;
      bf16x8_t b0 = *(const bf16x8_t*)(kr + row * 64 + 8 * (lg ^ (row & 7)));
      bf16x8_t b1 = *(const bf16x8_t*)(kr + row * 64 + 8 * ((lg + 4) ^ (row & 7)));
      f32x4_t s = {};
      s = __builtin_amdgcn_mfma_f32_16x16x32_bf16(b0, aQ0, s, 0, 0, 0);
      s = __builtin_amdgcn_mfma_f32_16x16x32_bf16(b1, aQ1, s, 0, 0, 0);
      sf[nt] = s;
    }

    // online softmax, log2 domain: in-lane 16 + 2 shfl_xor across lg-groups
    float tmax = sf[0][0];
#pragma unroll
    for (int nt = 0; nt < 4; ++nt)
#pragma unroll
      for (int e = 0; e < 4; ++e) tmax = fmaxf(tmax, sf[nt][e]);
    tmax = fmaxf(tmax, __shfl_xor(tmax, 16));
    tmax = fmaxf(tmax, __shfl_xor(tmax, 32));
    const float newm = fmaxf(mrow, tmax);
    const float sc = __builtin_amdgcn_exp2f(mrow - newm);
    float rsum = 0.f;
#pragma unroll
    for (int nt = 0; nt < 4; ++nt)
#pragma unroll
      for (int e = 0; e < 4; ++e) {
        float p = __builtin_amdgcn_exp2f(sf[nt][e] - newm);
        sf[nt][e] = p;
        rsum += p;
      }
    rsum += __shfl_xor(rsum, 16);
    rsum += __shfl_xor(rsum, 32);
    lrow = lrow * sc + rsum;
    mrow = newm;

    // P -> wave-private LDS: 4 packed b64 writes (k-contiguous per lane)
#pragma unroll
    for (int nt = 0; nt < 4; ++nt) {
      union { unsigned short s[4]; uint2 u; } pk;
#pragma unroll
      for (int e = 0; e < 4; ++e) {
        __hip_bfloat16 hv = __float2bfloat16(sf[nt][e]);
        pk.s[e] = *(unsigned short*)&hv;
      }
      const int off = lr * 64 + 8 * ((nt * 2 + (lg >> 1)) ^ (lr & 7)) + (lg & 1) * 4;
      *(uint2*)(pw + off) = pk.u;
    }

    // rescale acc by per-q factor (broadcast from lane lr=q within 16-group)
    float sce[4];
#pragma unroll
    for (int e = 0; e < 4; ++e) sce[e] = __shfl(sc, lg * 4 + e, 16);
#pragma unroll
    for (int dt = 0; dt < 4; ++dt)
#pragma unroll
      for (int e = 0; e < 4; ++e) acc[dt][e] *= sce[e];

    asm volatile("s_waitcnt lgkmcnt(0)" ::: "memory");
    const bf16x8_t aP0 = *(const bf16x8_t*)(pw + lr * 64 + 8 * (lg ^ (lr & 7)));
    const bf16x8_t aP1 = *(const bf16x8_t*)(pw + lr * 64 + 8 * ((lg + 4) ^ (lr & 7)));

    // ctx += P V
#pragma unroll
    for (int dt = 0; dt < 4; ++dt) {
      const int drow = dt * 16 + lr;
      bf16x8_t bv0 = *(const bf16x8_t*)(vr + drow * 64 + 8 * (lg ^ (drow & 7)));
      bf16x8_t bv1 = *(const bf16x8_t*)(vr + drow * 64 + 8 * ((lg + 4) ^ (drow & 7)));
      acc[dt] = __builtin_amdgcn_mfma_f32_16x16x32_bf16(aP0, bv0, acc[dt], 0, 0, 0);
      acc[dt] = __builtin_amdgcn_mfma_f32_16x16x32_bf16(aP1, bv1, acc[dt], 0, 0, 0);
    }
    asm volatile("" ::: "memory");
    __builtin_amdgcn_s_barrier();
  };

  const __hip_bfloat16* kb0 = &k_lds[0][0];
  const __hip_bfloat16* kb1 = &k_lds[1][0];
  const __hip_bfloat16* vb0 = &v_lds[0][0];
  const __hip_bfloat16* vb1 = &v_lds[1][0];
#pragma unroll 1
  for (int p = 0; p < 16; ++p) {
    tile(kb0, vb0, true, 2 * p + 1, kdst1, vdst1);
    tile(kb1, vb1, p < 15, 2 * p + 2, kdst0, vdst0);
  }

  // normalize + store ctx: q = lg*4+e, broadcast 1/l from lane lr=q
  const float inv = 1.0f / lrow;
  float inve[4];
#pragma unroll
  for (int e = 0; e < 4; ++e) inve[e] = __shfl(inv, lg * 4 + e, 16);
#pragma unroll
  for (int e = 0; e < 4; ++e) {
    const int row = q0 + w * 16 + lg * 4 + e;
#pragma unroll
    for (int dt = 0; dt < 4; ++dt) {
      const int d = dt * 16 + lr;
      ctx[((size_t)(b * T_SZ + row)) * 1024 + h * 64 + d] =
          __float2bfloat16(acc[dt][e] * inve[e]);
    }
  }
}

// ----------------------------------------------------------------- out GEMM
__global__ __launch_bounds__(256, 2) void gemm_out(
    const __hip_bfloat16* __restrict__ ctx, const __hip_bfloat16* __restrict__ wob,
    const float* __restrict__ bo, float* __restrict__ out) {
  __shared__ __hip_bfloat16 a_lds[8192];   // 2 buffers x 4096
  __shared__ __hip_bfloat16 b_lds[8192];
  // XCD swizzle: grid (8,32) -> 256 tiles; 32 consecutive tiles per XCD.
  const int lin = xcd_swz(blockIdx.y * 8 + blockIdx.x, 256);
  const int n0 = (lin % 8) * 128, m0 = (lin / 8) * 128;
  f32x4_t acc[4][4] = {};
  gemm_mainloop(ctx, wob, m0, n0, a_lds, b_lds, acc);
  const int tid = threadIdx.x;
  const int w = tid >> 6, l = tid & 63, lr = l & 15, lg = l >> 4;
  const int wm = w >> 1, wn = w & 1;
#pragma unroll
  for (int i = 0; i < 4; ++i) {
#pragma unroll
    for (int j = 0; j < 4; ++j) {
      const int col = n0 + wn * 64 + j * 16 + lr;
      const float bb = bo[col];
      f32x4_t v = acc[i][j];
#pragma unroll
      for (int e = 0; e < 4; ++e) {
        const int row = m0 + wm * 64 + i * 16 + lg * 4 + e;
        out[(size_t)row * 1024 + col] = v[e] + bb;
      }
    }
  }
}

// ------------------------------------------------------------------- launch
extern "C" void kernel_launch(void* const* d_in, const int* in_sizes, int n_in,
                              void* d_out, int out_size, void* d_ws, size_t ws_size,
                              hipStream_t stream) {
  const float* x  = (const float*)d_in[0];
  const float* wq = (const float*)d_in[1];
  const float* bq = (const float*)d_in[2];
  const float* wk = (const float*)d_in[3];
  const float* bk = (const float*)d_in[4];
  const float* wv = (const float*)d_in[5];
  const float* bv = (const float*)d_in[6];
  const float* wo = (const float*)d_in[7];
  const float* bo = (const float*)d_in[8];
  float* out = (float*)d_out;

  __hip_bfloat16* ws = (__hip_bfloat16*)d_ws;
  __hip_bfloat16* xb  = ws;
  __hip_bfloat16* wqb = xb + 4194304;
  __hip_bfloat16* wkb = wqb + 1048576;
  __hip_bfloat16* wvb = wkb + 1048576;
  __hip_bfloat16* wob = wvb + 1048576;
  __hip_bfloat16* qb  = wob + 1048576;
  __hip_bfloat16* kb  = qb + 4194304;
  __hip_bfloat16* vtb = kb + 4194304;
  __hip_bfloat16* ctxb = vtb + 4194304;

  cast_all_k<<<8192, 256, 0, stream>>>(x, wq, wk, wv, wo, xb);
  gemm_qkv<<<dim3(24, 32), 256, 0, stream>>>(xb, wqb, wkb, wvb, bq, bk, bv, qb, kb, vtb);
  attn_k<<<dim3(16, 32), 512, 0, stream>>>(qb, kb, vtb, ctxb);
  gemm_out<<<dim3(8, 32), 256, 0, stream>>>(ctxb, wob, bo, out);
}